// Round 14
// baseline (434.754 us; speedup 1.0000x reference)
//
#include <hip/hip_runtime.h>

constexpr int N_NODES = 100000;
constexpr int N_EDGES = 1600000;
constexpr int D_IN   = 512;
constexpr int H_DIM  = 128;
constexpr int D_OUT  = 64;
constexpr float ALPHA = 0.1f;

constexpr int SCAN_TPB = 256;                 // threads per scan block
constexpr int SCAN_EPB = SCAN_TPB * 8;        // 2048 elems per block
constexpr int SCAN_NB  = (N_NODES + SCAN_EPB - 1) / SCAN_EPB;   // 49

typedef __attribute__((ext_vector_type(4))) float f32x4;
typedef __attribute__((ext_vector_type(8))) short bf16x8;

__device__ __forceinline__ unsigned short f2bf(float f) {
    unsigned int u = __float_as_uint(f);
    u += 0x7fff + ((u >> 16) & 1);          // RNE
    return (unsigned short)(u >> 16);
}
__device__ __forceinline__ float bf2f(unsigned short b) {
    return __uint_as_float(((unsigned int)b) << 16);
}

// ---------------- CSC build ----------------
// NOTE: deg must be zeroed by a KERNEL, not hipMemsetAsync — the async memset
// was dropped from graph capture (r13: deg accumulated across replays, diverged).

__global__ void k_init(int* __restrict__ deg, int n) {
    int i = blockIdx.x * blockDim.x + threadIdx.x;
    if (i < n) deg[i] = 0;
}

// ---- fused weight prep bodies ----

constexpr int W1_E = D_IN * H_DIM;            // 65536
constexpr int CW_E = 2 * H_DIM * H_DIM;       // 32768
constexpr int W2_E = H_DIM * D_OUT;           // 8192
constexpr int WP_E = W1_E + CW_E + W2_E;      // 106496
constexpr int WP_NB = (WP_E + 255) / 256;     // 416

__device__ __forceinline__ void wprep_body(int i,
        const float* __restrict__ w1, const float* __restrict__ cw,
        const float* __restrict__ w2,
        unsigned short* __restrict__ w1th, unsigned short* __restrict__ w1tl,
        unsigned short* __restrict__ cwth, unsigned short* __restrict__ cwtl,
        unsigned short* __restrict__ w2th, unsigned short* __restrict__ w2tl) {
    const float* src; unsigned short *dh, *dl; int K, Nn, j;
    if (i < W1_E) {
        src = w1; dh = w1th; dl = w1tl; K = D_IN; Nn = H_DIM; j = i;
    } else if (i < W1_E + CW_E) {
        j = i - W1_E; int l = j >> 14; j &= 16383;
        src = cw + l * H_DIM * H_DIM; dh = cwth + l * H_DIM * H_DIM; dl = cwtl + l * H_DIM * H_DIM;
        K = H_DIM; Nn = H_DIM;
    } else if (i < WP_E) {
        j = i - W1_E - CW_E; src = w2; dh = w2th; dl = w2tl; K = H_DIM; Nn = D_OUT;
    } else return;
    int n = j / K, k = j % K;
    float v = src[(size_t)k * Nn + n];
    unsigned short h = f2bf(v);
    dh[j] = h;
    dl[j] = f2bf(v - bf2f(h));
}

// MEGA_A: degree count (family 0) + weight prep (family 1)
constexpr int CNT_NB = (N_EDGES + 255) / 256;   // 6250

__global__ __launch_bounds__(256) void k_mega_count_wprep(
        const int* __restrict__ col, int* __restrict__ deg,
        const float* __restrict__ w1, const float* __restrict__ cw, const float* __restrict__ w2,
        unsigned short* __restrict__ w1th, unsigned short* __restrict__ w1tl,
        unsigned short* __restrict__ cwth, unsigned short* __restrict__ cwtl,
        unsigned short* __restrict__ w2th, unsigned short* __restrict__ w2tl) {
    int b = blockIdx.x;
    if (b < CNT_NB) {
        int i = b * 256 + threadIdx.x;
        if (i < N_EDGES) atomicAdd(&deg[col[i]], 1);
    } else {
        int i = (b - CNT_NB) * 256 + threadIdx.x;
        wprep_body(i, w1, cw, w2, w1th, w1tl, cwth, cwtl, w2th, w2tl);
    }
}

// ---- 3-phase hierarchical exclusive scan of deg -> offsets (+cursor preload, +dinv) ----

__global__ __launch_bounds__(SCAN_TPB) void k_scan_part(const int* __restrict__ deg,
                                                        int* __restrict__ partials, int n) {
    __shared__ int red[SCAN_TPB];
    int t = threadIdx.x;
    int base = blockIdx.x * SCAN_EPB + t * 8;
    int s = 0;
    if (base + 8 <= n) {
        int4 a = *(const int4*)(deg + base);
        int4 b = *(const int4*)(deg + base + 4);
        s = a.x + a.y + a.z + a.w + b.x + b.y + b.z + b.w;
    } else {
        for (int j = 0; j < 8; ++j) if (base + j < n) s += deg[base + j];
    }
    red[t] = s;
    __syncthreads();
    for (int off = SCAN_TPB / 2; off > 0; off >>= 1) {
        if (t < off) red[t] += red[t + off];
        __syncthreads();
    }
    if (t == 0) partials[blockIdx.x] = red[0];
}

__global__ __launch_bounds__(64) void k_scan_mid(int* __restrict__ partials,
                                                 int* __restrict__ offsets) {
    __shared__ int buf[SCAN_NB];
    int t = threadIdx.x;
    if (t < SCAN_NB) buf[t] = partials[t];
    __syncthreads();
    if (t == 0) {
        int run = 0;
        for (int i = 0; i < SCAN_NB; ++i) { int v = buf[i]; buf[i] = run; run += v; }
        offsets[N_NODES] = run;    // == E
    }
    __syncthreads();
    if (t < SCAN_NB) partials[t] = buf[t];
}

__global__ __launch_bounds__(SCAN_TPB) void k_scan_write(const int* __restrict__ deg,
                                                         const int* __restrict__ partials,
                                                         int* __restrict__ offsets,
                                                         int* __restrict__ cursor,
                                                         float* __restrict__ dinv, int n) {
    __shared__ int sums[SCAN_TPB];
    int t = threadIdx.x;
    int base = blockIdx.x * SCAN_EPB + t * 8;
    int v[8];
    if (base + 8 <= n) {
        int4 a = *(const int4*)(deg + base);
        int4 b = *(const int4*)(deg + base + 4);
        v[0] = a.x; v[1] = a.y; v[2] = a.z; v[3] = a.w;
        v[4] = b.x; v[5] = b.y; v[6] = b.z; v[7] = b.w;
    } else {
        for (int j = 0; j < 8; ++j) v[j] = (base + j < n) ? deg[base + j] : 0;
    }
    int p[8], s = 0;
#pragma unroll
    for (int j = 0; j < 8; ++j) { p[j] = s; s += v[j]; }
    sums[t] = s;
    __syncthreads();
    for (int off = 1; off < SCAN_TPB; off <<= 1) {
        int add = (t >= off) ? sums[t - off] : 0;
        __syncthreads();
        sums[t] += add;
        __syncthreads();
    }
    int tbase = partials[blockIdx.x] + ((t == 0) ? 0 : sums[t - 1]);
#pragma unroll
    for (int j = 0; j < 8; ++j)
        if (base + j < n) {
            int o = tbase + p[j];
            offsets[base + j] = o;
            cursor[base + j] = o;                       // k_fill skips offsets gather
            dinv[base + j] = rsqrtf((float)(v[j] + 1)); // fused k_dinv (+1 self loop)
        }
}

// fill: one 8B packed scatter per edge; standalone (no LDS) -> ~8 blocks/CU occupancy.
// (Co-scheduling with lin1 tried r11/r12: GEMM's 40KB LDS cut fill residency, net loss.)
__global__ void k_fill(const int* __restrict__ row, const int* __restrict__ col,
                       int* __restrict__ cursor, const float* __restrict__ dinv,
                       int2* __restrict__ edges, int e) {
    int i = blockIdx.x * blockDim.x + threadIdx.x;
    if (i >= e) return;
    int r = row[i], c = col[i];
    int p = atomicAdd(&cursor[c], 1);
    int2 v;
    v.x = r;
    v.y = __float_as_int(dinv[r] * dinv[c]);
    edges[p] = v;
}

// ---------------- aggregation: one wave per node, bf16 gather, 8x unroll ----------------
// zb = bf16( (1-a) * (dinv_i^2 * hb[i] + sum_in norm * hb[src]) + a * h0b[i] )

__global__ __launch_bounds__(256) void k_agg(
        const unsigned short* __restrict__ hb,   // bf16 rows [N][128] (current h)
        const unsigned short* __restrict__ h0b,  // bf16 residual
        const int* __restrict__ offsets, const int2* __restrict__ edges,
        const float* __restrict__ dinv,
        unsigned short* __restrict__ zb, int n) {
    int wid  = (int)((blockIdx.x * (unsigned)blockDim.x + threadIdx.x) >> 6);
    int lane = threadIdx.x & 63;
    if (wid >= n) return;
    float di = dinv[wid];
    const float oma = 1.0f - ALPHA;
    int o0 = offsets[wid], o1 = offsets[wid + 1];
    ushort2 hc = ((const ushort2*)(hb  + (size_t)wid * H_DIM))[lane];
    ushort2 hz = ((const ushort2*)(h0b + (size_t)wid * H_DIM))[lane];
    float sw = oma * di * di;
    float accx = sw * bf2f(hc.x) + ALPHA * bf2f(hz.x);
    float accy = sw * bf2f(hc.y) + ALPHA * bf2f(hz.y);
    int p2 = o0;
    for (; p2 + 8 <= o1; p2 += 8) {
        int2 e[8];
        ushort2 g[8];
#pragma unroll
        for (int j = 0; j < 8; ++j) e[j] = edges[p2 + j];
#pragma unroll
        for (int j = 0; j < 8; ++j)
            g[j] = ((const ushort2*)(hb + (size_t)e[j].x * H_DIM))[lane];
#pragma unroll
        for (int j = 0; j < 8; ++j) {
            float w = oma * __int_as_float(e[j].y);
            accx += w * bf2f(g[j].x);
            accy += w * bf2f(g[j].y);
        }
    }
    for (; p2 < o1; ++p2) {
        int2 e = edges[p2];
        float wv = oma * __int_as_float(e.y);
        ushort2 g = ((const ushort2*)(hb + (size_t)e.x * H_DIM))[lane];
        accx += wv * bf2f(g.x); accy += wv * bf2f(g.y);
    }
    ushort2 o; o.x = f2bf(accx); o.y = f2bf(accy);
    ((ushort2*)(zb + (size_t)wid * H_DIM))[lane] = o;
}

// ---------------- bf16-activation MFMA GEMM body (shared) ----------------
// C = act(A @ B + bias); A bf16 (AF32: converted from f32 during staging).
// B f32-accurate via hi/lo: acc += Ah*Bh + Ah*Bl (2 MFMA).

template<int BN, bool AF32, bool RELU, bool BIAS, bool WF32, bool WB16>
__device__ __forceinline__ void gemm_body(
        char* AhC, char* BhC, char* BlC, int bm, int tid,
        const float* __restrict__ Af,
        const unsigned short* __restrict__ Ab,
        const unsigned short* __restrict__ Bth,
        const unsigned short* __restrict__ Btl,
        const float* __restrict__ bias,
        float* __restrict__ C, unsigned short* __restrict__ Cb,
        int M, int K) {
    constexpr int BM = 64, BK = 64;
    constexpr int WN = BN / 2;
    constexpr int NF = WN / 16;
    const int wave = tid >> 6, lane = tid & 63;
    const int wrow = wave >> 1, wcol = wave & 1;
    const int l15 = lane & 15, l4 = lane >> 4;

    f32x4 acc[2][NF];
#pragma unroll
    for (int mf = 0; mf < 2; ++mf)
#pragma unroll
        for (int nf = 0; nf < NF; ++nf) acc[mf][nf] = (f32x4){0.f, 0.f, 0.f, 0.f};

    for (int k0 = 0; k0 < K; k0 += BK) {
#pragma unroll
        for (int c = 0; c < (BM * 8) / 256; ++c) {
            int ch = tid + c * 256;
            int m = ch >> 3, kc = (ch & 7) * 8;
            int gr = bm + m;
            bf16x8 hv;
            if constexpr (AF32) {
                float v[8];
                if (gr < M) {
                    const float4* src = (const float4*)(Af + (size_t)gr * K + k0 + kc);
                    float4 a0 = src[0], a1 = src[1];
                    v[0] = a0.x; v[1] = a0.y; v[2] = a0.z; v[3] = a0.w;
                    v[4] = a1.x; v[5] = a1.y; v[6] = a1.z; v[7] = a1.w;
                } else {
#pragma unroll
                    for (int j = 0; j < 8; ++j) v[j] = 0.f;
                }
#pragma unroll
                for (int j = 0; j < 8; ++j) hv[j] = (short)f2bf(v[j]);
            } else {
                if (gr < M) {
                    hv = *(const bf16x8*)(Ab + (size_t)gr * K + k0 + kc);
                } else {
                    hv = (bf16x8){0, 0, 0, 0, 0, 0, 0, 0};
                }
            }
            int byte = ((m * BK + kc) * 2) ^ ((m & 7) << 4);
            *(bf16x8*)(AhC + byte) = hv;
        }
#pragma unroll
        for (int c = 0; c < (BN * 8) / 256; ++c) {
            int ch = tid + c * 256;
            int n = ch >> 3, kc = (ch & 7) * 8;
            bf16x8 hv = *(const bf16x8*)(Bth + (size_t)n * K + k0 + kc);
            bf16x8 lv = *(const bf16x8*)(Btl + (size_t)n * K + k0 + kc);
            int byte = ((n * BK + kc) * 2) ^ ((n & 7) << 4);
            *(bf16x8*)(BhC + byte) = hv;
            *(bf16x8*)(BlC + byte) = lv;
        }
        __syncthreads();
#pragma unroll
        for (int ks = 0; ks < 2; ++ks) {
            bf16x8 ah[2], bh[NF], bl[NF];
#pragma unroll
            for (int mf = 0; mf < 2; ++mf) {
                int row = wrow * 32 + mf * 16 + l15;
                int byte = ((row * BK + ks * 32 + l4 * 8) * 2) ^ ((row & 7) << 4);
                ah[mf] = *(const bf16x8*)(AhC + byte);
            }
#pragma unroll
            for (int nf = 0; nf < NF; ++nf) {
                int n = wcol * WN + nf * 16 + l15;
                int byte = ((n * BK + ks * 32 + l4 * 8) * 2) ^ ((n & 7) << 4);
                bh[nf] = *(const bf16x8*)(BhC + byte);
                bl[nf] = *(const bf16x8*)(BlC + byte);
            }
#pragma unroll
            for (int mf = 0; mf < 2; ++mf)
#pragma unroll
                for (int nf = 0; nf < NF; ++nf) {
                    acc[mf][nf] = __builtin_amdgcn_mfma_f32_16x16x32_bf16(ah[mf], bh[nf], acc[mf][nf], 0, 0, 0);
                    acc[mf][nf] = __builtin_amdgcn_mfma_f32_16x16x32_bf16(ah[mf], bl[nf], acc[mf][nf], 0, 0, 0);
                }
        }
        __syncthreads();
    }
#pragma unroll
    for (int mf = 0; mf < 2; ++mf) {
#pragma unroll
        for (int nf = 0; nf < NF; ++nf) {
            int col = wcol * WN + nf * 16 + l15;
            float bv = 0.f;
            if constexpr (BIAS) bv = bias[col];
#pragma unroll
            for (int r = 0; r < 4; ++r) {
                int grow = bm + wrow * 32 + mf * 16 + l4 * 4 + r;
                if (grow < M) {
                    float v = acc[mf][nf][r] + bv;
                    if constexpr (RELU) v = fmaxf(v, 0.f);
                    if constexpr (WF32) C[(size_t)grow * BN + col] = v;
                    if constexpr (WB16) Cb[(size_t)grow * BN + col] = f2bf(v);
                }
            }
        }
    }
}

// plain GEMM kernel (lin1, conv layer 0)
template<int BN, bool AF32, bool RELU, bool BIAS, bool WF32, bool WB16>
__global__ __launch_bounds__(256, 4) void k_mfma_gemm(
        const float* __restrict__ Af,
        const unsigned short* __restrict__ Ab,
        const unsigned short* __restrict__ Bth,
        const unsigned short* __restrict__ Btl,
        const float* __restrict__ bias,
        float* __restrict__ C, unsigned short* __restrict__ Cb,
        int M, int K) {
    __shared__ char lds[(64 + 2 * BN) * 64 * 2];
    gemm_body<BN, AF32, RELU, BIAS, WF32, WB16>(
        lds, lds + 64 * 64 * 2, lds + (64 + BN) * 64 * 2,
        blockIdx.x * 64, threadIdx.x, Af, Ab, Bth, Btl, bias, C, Cb, M, K);
}

// ---------------- fused conv-layer-1 + logits kernel ----------------

__global__ __launch_bounds__(256, 3) void k_conv1_logits(
        const unsigned short* __restrict__ Ab,     // zb [M][128]
        const unsigned short* __restrict__ Bth,    // cw1 hi [128][128]
        const unsigned short* __restrict__ Btl,    // cw1 lo
        const unsigned short* __restrict__ W2h,    // w2 hi [64][128]
        const unsigned short* __restrict__ W2l,    // w2 lo
        const float* __restrict__ b2,
        float* __restrict__ h2, float* __restrict__ logits, int M) {
    constexpr int BM = 64, BK = 64, BN = 128, K = 128;
    constexpr int WN = BN / 2, NF = WN / 16;
    __shared__ char lds[49152];
    char* AhC = lds;                 // phase1 A: [64][64] bf16, 8 KB
    char* BhC = lds + 8192;          // phase1 B hi: [128][64], 16 KB
    char* BlC = lds + 24576;         // phase1 B lo: [128][64], 16 KB
    char* A2C = lds;                 // phase2 A: [64][128] bf16, 16 KB
    char* WhC = lds + 16384;         // phase2 w2 hi: [64][128], 16 KB
    char* WlC = lds + 32768;         // phase2 w2 lo: [64][128], 16 KB
    const int tid = threadIdx.x;
    const int wave = tid >> 6, lane = tid & 63;
    const int wrow = wave >> 1, wcol = wave & 1;
    const int l15 = lane & 15, l4 = lane >> 4;
    const int bm = blockIdx.x * BM;

    f32x4 acc[2][NF];
#pragma unroll
    for (int mf = 0; mf < 2; ++mf)
#pragma unroll
        for (int nf = 0; nf < NF; ++nf) acc[mf][nf] = (f32x4){0.f, 0.f, 0.f, 0.f};

    for (int k0 = 0; k0 < K; k0 += BK) {
#pragma unroll
        for (int c = 0; c < (BM * 8) / 256; ++c) {
            int ch = tid + c * 256;
            int m = ch >> 3, kc = (ch & 7) * 8;
            int gr = bm + m;
            bf16x8 hv;
            if (gr < M) hv = *(const bf16x8*)(Ab + (size_t)gr * K + k0 + kc);
            else        hv = (bf16x8){0, 0, 0, 0, 0, 0, 0, 0};
            int byte = ((m * BK + kc) * 2) ^ ((m & 7) << 4);
            *(bf16x8*)(AhC + byte) = hv;
        }
#pragma unroll
        for (int c = 0; c < (BN * 8) / 256; ++c) {
            int ch = tid + c * 256;
            int n = ch >> 3, kc = (ch & 7) * 8;
            bf16x8 hv = *(const bf16x8*)(Bth + (size_t)n * K + k0 + kc);
            bf16x8 lv = *(const bf16x8*)(Btl + (size_t)n * K + k0 + kc);
            int byte = ((n * BK + kc) * 2) ^ ((n & 7) << 4);
            *(bf16x8*)(BhC + byte) = hv;
            *(bf16x8*)(BlC + byte) = lv;
        }
        __syncthreads();
#pragma unroll
        for (int ks = 0; ks < 2; ++ks) {
            bf16x8 ah[2], bh[NF], bl[NF];
#pragma unroll
            for (int mf = 0; mf < 2; ++mf) {
                int row = wrow * 32 + mf * 16 + l15;
                int byte = ((row * BK + ks * 32 + l4 * 8) * 2) ^ ((row & 7) << 4);
                ah[mf] = *(const bf16x8*)(AhC + byte);
            }
#pragma unroll
            for (int nf = 0; nf < NF; ++nf) {
                int n = wcol * WN + nf * 16 + l15;
                int byte = ((n * BK + ks * 32 + l4 * 8) * 2) ^ ((n & 7) << 4);
                bh[nf] = *(const bf16x8*)(BhC + byte);
                bl[nf] = *(const bf16x8*)(BlC + byte);
            }
#pragma unroll
            for (int mf = 0; mf < 2; ++mf)
#pragma unroll
                for (int nf = 0; nf < NF; ++nf) {
                    acc[mf][nf] = __builtin_amdgcn_mfma_f32_16x16x32_bf16(ah[mf], bh[nf], acc[mf][nf], 0, 0, 0);
                    acc[mf][nf] = __builtin_amdgcn_mfma_f32_16x16x32_bf16(ah[mf], bl[nf], acc[mf][nf], 0, 0, 0);
                }
        }
        __syncthreads();
    }
    // epilogue: write h2 f32 (global) + bf16 h2 tile to LDS A2 [64][128] swizzled
#pragma unroll
    for (int mf = 0; mf < 2; ++mf) {
#pragma unroll
        for (int nf = 0; nf < NF; ++nf) {
            int col = wcol * WN + nf * 16 + l15;
#pragma unroll
            for (int r = 0; r < 4; ++r) {
                int mrow = wrow * 32 + mf * 16 + l4 * 4 + r;
                int grow = bm + mrow;
                float v = acc[mf][nf][r];
                if (grow < M) h2[(size_t)grow * BN + col] = v;
                int byte = ((mrow * 128 + col) * 2) ^ ((mrow & 7) << 4);
                *(unsigned short*)(A2C + byte) = f2bf(v);
            }
        }
    }
    // stage w2 hi/lo [64][128] into LDS
#pragma unroll
    for (int c = 0; c < 4; ++c) {
        int ch = tid + c * 256;
        int n = ch >> 4, kc = (ch & 15) * 8;
        bf16x8 hv = *(const bf16x8*)(W2h + (size_t)n * 128 + kc);
        bf16x8 lv = *(const bf16x8*)(W2l + (size_t)n * 128 + kc);
        int byte = ((n * 128 + kc) * 2) ^ ((n & 7) << 4);
        *(bf16x8*)(WhC + byte) = hv;
        *(bf16x8*)(WlC + byte) = lv;
    }
    __syncthreads();

    // phase 2: logits = A2 @ w2 + b2
    f32x4 acc2[2][2];
#pragma unroll
    for (int mf = 0; mf < 2; ++mf)
#pragma unroll
        for (int nf = 0; nf < 2; ++nf) acc2[mf][nf] = (f32x4){0.f, 0.f, 0.f, 0.f};
#pragma unroll
    for (int ks = 0; ks < 4; ++ks) {
        bf16x8 a2[2], wh[2], wl[2];
#pragma unroll
        for (int mf = 0; mf < 2; ++mf) {
            int row = wrow * 32 + mf * 16 + l15;
            int byte = ((row * 128 + ks * 32 + l4 * 8) * 2) ^ ((row & 7) << 4);
            a2[mf] = *(const bf16x8*)(A2C + byte);
        }
#pragma unroll
        for (int nf = 0; nf < 2; ++nf) {
            int n = wcol * 32 + nf * 16 + l15;
            int byte = ((n * 128 + ks * 32 + l4 * 8) * 2) ^ ((n & 7) << 4);
            wh[nf] = *(const bf16x8*)(WhC + byte);
            wl[nf] = *(const bf16x8*)(WlC + byte);
        }
#pragma unroll
        for (int mf = 0; mf < 2; ++mf)
#pragma unroll
            for (int nf = 0; nf < 2; ++nf) {
                acc2[mf][nf] = __builtin_amdgcn_mfma_f32_16x16x32_bf16(a2[mf], wh[nf], acc2[mf][nf], 0, 0, 0);
                acc2[mf][nf] = __builtin_amdgcn_mfma_f32_16x16x32_bf16(a2[mf], wl[nf], acc2[mf][nf], 0, 0, 0);
            }
    }
#pragma unroll
    for (int mf = 0; mf < 2; ++mf) {
#pragma unroll
        for (int nf = 0; nf < 2; ++nf) {
            int col = wcol * 32 + nf * 16 + l15;
            float bv = b2[col];
#pragma unroll
            for (int r = 0; r < 4; ++r) {
                int grow = bm + wrow * 32 + mf * 16 + l4 * 4 + r;
                if (grow < M)
                    logits[(size_t)grow * D_OUT + col] = acc2[mf][nf][r] + bv;
            }
        }
    }
}

// ---------------- launch ----------------

extern "C" void kernel_launch(void* const* d_in, const int* in_sizes, int n_in,
                              void* d_out, int out_size, void* d_ws, size_t ws_size,
                              hipStream_t stream) {
    const float* x  = (const float*)d_in[0];
    const int*   ei = (const int*)d_in[1];
    const float* w1 = (const float*)d_in[2];
    const float* b1 = (const float*)d_in[3];
    const float* cw = (const float*)d_in[4];
    const float* w2 = (const float*)d_in[5];
    const float* b2 = (const float*)d_in[6];
    float* out = (float*)d_out;
    const int* rowp = ei;            // source nodes
    const int* colp = ei + N_EDGES;  // target nodes

    char* p = (char*)d_ws;
    auto alloc = [&](size_t bytes) -> void* {
        void* r = (void*)p;
        p += ((bytes + 255) / 256) * 256;
        return r;
    };
    int*   deg     = (int*)  alloc((size_t)N_NODES * 4);
    int*   cursor  = (int*)  alloc((size_t)N_NODES * 4);
    int*   offsets = (int*)  alloc((size_t)(N_NODES + 1) * 4);
    int*   partials= (int*)  alloc((size_t)SCAN_NB * 4);
    int2*  edges   = (int2*) alloc((size_t)N_EDGES * 8);
    float* dinv    = (float*)alloc((size_t)N_NODES * 4);
    unsigned short* zb  = (unsigned short*)alloc((size_t)N_NODES * H_DIM * 2);
    unsigned short* h0b = (unsigned short*)alloc((size_t)N_NODES * H_DIM * 2);
    unsigned short* h1b = (unsigned short*)alloc((size_t)N_NODES * H_DIM * 2);
    unsigned short* w1th = (unsigned short*)alloc((size_t)W1_E * 2);
    unsigned short* w1tl = (unsigned short*)alloc((size_t)W1_E * 2);
    unsigned short* cwth = (unsigned short*)alloc((size_t)CW_E * 2);
    unsigned short* cwtl = (unsigned short*)alloc((size_t)CW_E * 2);
    unsigned short* w2th = (unsigned short*)alloc((size_t)W2_E * 2);
    unsigned short* w2tl = (unsigned short*)alloc((size_t)W2_E * 2);

    float* h2     = out;                              // output 0: h [N,128]
    float* logits = out + (size_t)N_NODES * H_DIM;    // output 1: [N,64]

    // deg = 0 (kernel — NOT hipMemsetAsync; see r13 note above)
    hipLaunchKernelGGL(k_init, dim3((N_NODES + 255) / 256), dim3(256), 0, stream, deg, N_NODES);
    // CSC degree count + weight prep (co-scheduled)
    hipLaunchKernelGGL(k_mega_count_wprep, dim3(CNT_NB + WP_NB), dim3(256), 0, stream,
                       colp, deg, w1, cw, w2, w1th, w1tl, cwth, cwtl, w2th, w2tl);
    hipLaunchKernelGGL(k_scan_part,  dim3(SCAN_NB), dim3(SCAN_TPB), 0, stream, deg, partials, N_NODES);
    hipLaunchKernelGGL(k_scan_mid,   dim3(1), dim3(64), 0, stream, partials, offsets);
    hipLaunchKernelGGL(k_scan_write, dim3(SCAN_NB), dim3(SCAN_TPB), 0, stream,
                       deg, partials, offsets, cursor, dinv, N_NODES);

    // edge fill: standalone, max occupancy
    hipLaunchKernelGGL(k_fill, dim3((N_EDGES + 255) / 256), dim3(256), 0, stream,
                       rowp, colp, cursor, dinv, edges, N_EDGES);

    int gemmGrid = (N_NODES + 63) / 64;
    int aggGrid = (int)(((size_t)N_NODES * 64 + 255) / 256);
    // lin1: h0b = bf16(relu(x @ w1 + b1))
    hipLaunchKernelGGL((k_mfma_gemm<128, true, true, true, false, true>), dim3(gemmGrid), dim3(256), 0, stream,
                       x, (const unsigned short*)nullptr, w1th, w1tl, b1,
                       (float*)nullptr, h0b, N_NODES, D_IN);
    // layer 0
    hipLaunchKernelGGL(k_agg, dim3(aggGrid), dim3(256), 0, stream,
                       h0b, h0b, offsets, edges, dinv, zb, N_NODES);
    hipLaunchKernelGGL((k_mfma_gemm<128, false, false, false, false, true>), dim3(gemmGrid), dim3(256), 0, stream,
                       (const float*)nullptr, zb, cwth, cwtl, (const float*)nullptr,
                       (float*)nullptr, h1b, N_NODES, H_DIM);
    // layer 1
    hipLaunchKernelGGL(k_agg, dim3(aggGrid), dim3(256), 0, stream,
                       h1b, h0b, offsets, edges, dinv, zb, N_NODES);
    // conv1 + logits fused
    hipLaunchKernelGGL(k_conv1_logits, dim3(gemmGrid), dim3(256), 0, stream,
                       zb, cwth + H_DIM * H_DIM, cwtl + H_DIM * H_DIM,
                       w2th, w2tl, b2, h2, logits, N_NODES);
}

// Round 15
// 416.081 us; speedup vs baseline: 1.0449x; 1.0449x over previous
//
#include <hip/hip_runtime.h>

constexpr int N_NODES = 100000;
constexpr int N_EDGES = 1600000;
constexpr int D_IN   = 512;
constexpr int H_DIM  = 128;
constexpr int D_OUT  = 64;
constexpr float ALPHA = 0.1f;

constexpr int SCAN_TPB = 256;                 // threads per scan block
constexpr int SCAN_EPB = SCAN_TPB * 8;        // 2048 elems per block
constexpr int SCAN_NB  = (N_NODES + SCAN_EPB - 1) / SCAN_EPB;   // 49

typedef __attribute__((ext_vector_type(4))) float f32x4;
typedef __attribute__((ext_vector_type(8))) short bf16x8;

__device__ __forceinline__ unsigned short f2bf(float f) {
    unsigned int u = __float_as_uint(f);
    u += 0x7fff + ((u >> 16) & 1);          // RNE
    return (unsigned short)(u >> 16);
}
__device__ __forceinline__ float bf2f(unsigned short b) {
    return __uint_as_float(((unsigned int)b) << 16);
}

// ---------------- CSC build ----------------
// NOTE: deg must be zeroed by a KERNEL, not hipMemsetAsync (r13: async memset
// dropped from graph capture -> deg accumulated across replays, diverged).

__global__ void k_init(int* __restrict__ deg, int n) {
    int i = blockIdx.x * blockDim.x + threadIdx.x;
    if (i < n) deg[i] = 0;
}

// ---- fused weight prep bodies ----

constexpr int W1_E = D_IN * H_DIM;            // 65536
constexpr int CW_E = 2 * H_DIM * H_DIM;       // 32768
constexpr int W2_E = H_DIM * D_OUT;           // 8192
constexpr int WP_E = W1_E + CW_E + W2_E;      // 106496
constexpr int WP_NB = (WP_E + 255) / 256;     // 416

__device__ __forceinline__ void wprep_body(int i,
        const float* __restrict__ w1, const float* __restrict__ cw,
        const float* __restrict__ w2,
        unsigned short* __restrict__ w1th, unsigned short* __restrict__ w1tl,
        unsigned short* __restrict__ cwth, unsigned short* __restrict__ cwtl,
        unsigned short* __restrict__ w2th, unsigned short* __restrict__ w2tl) {
    const float* src; unsigned short *dh, *dl; int K, Nn, j;
    if (i < W1_E) {
        src = w1; dh = w1th; dl = w1tl; K = D_IN; Nn = H_DIM; j = i;
    } else if (i < W1_E + CW_E) {
        j = i - W1_E; int l = j >> 14; j &= 16383;
        src = cw + l * H_DIM * H_DIM; dh = cwth + l * H_DIM * H_DIM; dl = cwtl + l * H_DIM * H_DIM;
        K = H_DIM; Nn = H_DIM;
    } else if (i < WP_E) {
        j = i - W1_E - CW_E; src = w2; dh = w2th; dl = w2tl; K = H_DIM; Nn = D_OUT;
    } else return;
    int n = j / K, k = j % K;
    float v = src[(size_t)k * Nn + n];
    unsigned short h = f2bf(v);
    dh[j] = h;
    dl[j] = f2bf(v - bf2f(h));
}

// MEGA_A: degree count (family 0) + weight prep (family 1)
constexpr int CNT_NB = (N_EDGES + 255) / 256;   // 6250

__global__ __launch_bounds__(256) void k_mega_count_wprep(
        const int* __restrict__ col, int* __restrict__ deg,
        const float* __restrict__ w1, const float* __restrict__ cw, const float* __restrict__ w2,
        unsigned short* __restrict__ w1th, unsigned short* __restrict__ w1tl,
        unsigned short* __restrict__ cwth, unsigned short* __restrict__ cwtl,
        unsigned short* __restrict__ w2th, unsigned short* __restrict__ w2tl) {
    int b = blockIdx.x;
    if (b < CNT_NB) {
        int i = b * 256 + threadIdx.x;
        if (i < N_EDGES) atomicAdd(&deg[col[i]], 1);
    } else {
        int i = (b - CNT_NB) * 256 + threadIdx.x;
        wprep_body(i, w1, cw, w2, w1th, w1tl, cwth, cwtl, w2th, w2tl);
    }
}

// ---- 3-phase hierarchical exclusive scan of deg -> offsets (+cursor preload, +dinv) ----

__global__ __launch_bounds__(SCAN_TPB) void k_scan_part(const int* __restrict__ deg,
                                                        int* __restrict__ partials, int n) {
    __shared__ int red[SCAN_TPB];
    int t = threadIdx.x;
    int base = blockIdx.x * SCAN_EPB + t * 8;
    int s = 0;
    if (base + 8 <= n) {
        int4 a = *(const int4*)(deg + base);
        int4 b = *(const int4*)(deg + base + 4);
        s = a.x + a.y + a.z + a.w + b.x + b.y + b.z + b.w;
    } else {
        for (int j = 0; j < 8; ++j) if (base + j < n) s += deg[base + j];
    }
    red[t] = s;
    __syncthreads();
    for (int off = SCAN_TPB / 2; off > 0; off >>= 1) {
        if (t < off) red[t] += red[t + off];
        __syncthreads();
    }
    if (t == 0) partials[blockIdx.x] = red[0];
}

__global__ __launch_bounds__(64) void k_scan_mid(int* __restrict__ partials,
                                                 int* __restrict__ offsets) {
    __shared__ int buf[SCAN_NB];
    int t = threadIdx.x;
    if (t < SCAN_NB) buf[t] = partials[t];
    __syncthreads();
    if (t == 0) {
        int run = 0;
        for (int i = 0; i < SCAN_NB; ++i) { int v = buf[i]; buf[i] = run; run += v; }
        offsets[N_NODES] = run;    // == E
    }
    __syncthreads();
    if (t < SCAN_NB) partials[t] = buf[t];
}

__global__ __launch_bounds__(SCAN_TPB) void k_scan_write(const int* __restrict__ deg,
                                                         const int* __restrict__ partials,
                                                         int* __restrict__ offsets,
                                                         int* __restrict__ cursor,
                                                         float* __restrict__ dinv, int n) {
    __shared__ int sums[SCAN_TPB];
    int t = threadIdx.x;
    int base = blockIdx.x * SCAN_EPB + t * 8;
    int v[8];
    if (base + 8 <= n) {
        int4 a = *(const int4*)(deg + base);
        int4 b = *(const int4*)(deg + base + 4);
        v[0] = a.x; v[1] = a.y; v[2] = a.z; v[3] = a.w;
        v[4] = b.x; v[5] = b.y; v[6] = b.z; v[7] = b.w;
    } else {
        for (int j = 0; j < 8; ++j) v[j] = (base + j < n) ? deg[base + j] : 0;
    }
    int p[8], s = 0;
#pragma unroll
    for (int j = 0; j < 8; ++j) { p[j] = s; s += v[j]; }
    sums[t] = s;
    __syncthreads();
    for (int off = 1; off < SCAN_TPB; off <<= 1) {
        int add = (t >= off) ? sums[t - off] : 0;
        __syncthreads();
        sums[t] += add;
        __syncthreads();
    }
    int tbase = partials[blockIdx.x] + ((t == 0) ? 0 : sums[t - 1]);
#pragma unroll
    for (int j = 0; j < 8; ++j)
        if (base + j < n) {
            int o = tbase + p[j];
            offsets[base + j] = o;
            cursor[base + j] = o;                       // k_fill skips offsets gather
            dinv[base + j] = rsqrtf((float)(v[j] + 1)); // fused k_dinv (+1 self loop)
        }
}

// ---------------- aggregation: one wave per node, bf16 gather, 8x unroll ----------------
// zb = bf16( (1-a) * (dinv_i^2 * hb[i] + sum_in norm * hb[src]) + a * h0b[i] )

__global__ __launch_bounds__(256) void k_agg(
        const unsigned short* __restrict__ hb,   // bf16 rows [N][128] (current h)
        const unsigned short* __restrict__ h0b,  // bf16 residual
        const int* __restrict__ offsets, const int2* __restrict__ edges,
        const float* __restrict__ dinv,
        unsigned short* __restrict__ zb, int n) {
    int wid  = (int)((blockIdx.x * (unsigned)blockDim.x + threadIdx.x) >> 6);
    int lane = threadIdx.x & 63;
    if (wid >= n) return;
    float di = dinv[wid];
    const float oma = 1.0f - ALPHA;
    int o0 = offsets[wid], o1 = offsets[wid + 1];
    ushort2 hc = ((const ushort2*)(hb  + (size_t)wid * H_DIM))[lane];
    ushort2 hz = ((const ushort2*)(h0b + (size_t)wid * H_DIM))[lane];
    float sw = oma * di * di;
    float accx = sw * bf2f(hc.x) + ALPHA * bf2f(hz.x);
    float accy = sw * bf2f(hc.y) + ALPHA * bf2f(hz.y);
    int p2 = o0;
    for (; p2 + 8 <= o1; p2 += 8) {
        int2 e[8];
        ushort2 g[8];
#pragma unroll
        for (int j = 0; j < 8; ++j) e[j] = edges[p2 + j];
#pragma unroll
        for (int j = 0; j < 8; ++j)
            g[j] = ((const ushort2*)(hb + (size_t)e[j].x * H_DIM))[lane];
#pragma unroll
        for (int j = 0; j < 8; ++j) {
            float w = oma * __int_as_float(e[j].y);
            accx += w * bf2f(g[j].x);
            accy += w * bf2f(g[j].y);
        }
    }
    for (; p2 < o1; ++p2) {
        int2 e = edges[p2];
        float wv = oma * __int_as_float(e.y);
        ushort2 g = ((const ushort2*)(hb + (size_t)e.x * H_DIM))[lane];
        accx += wv * bf2f(g.x); accy += wv * bf2f(g.y);
    }
    ushort2 o; o.x = f2bf(accx); o.y = f2bf(accy);
    ((ushort2*)(zb + (size_t)wid * H_DIM))[lane] = o;
}

// ---------------- bf16-activation MFMA GEMM body (shared) ----------------
// C = act(A @ B + bias); A bf16 (AF32: converted from f32 during staging).
// B f32-accurate via hi/lo: acc += Ah*Bh + Ah*Bl (2 MFMA).

template<int BN, bool AF32, bool RELU, bool BIAS, bool WF32, bool WB16>
__device__ __forceinline__ void gemm_body(
        char* AhC, char* BhC, char* BlC, int bm, int tid,
        const float* __restrict__ Af,
        const unsigned short* __restrict__ Ab,
        const unsigned short* __restrict__ Bth,
        const unsigned short* __restrict__ Btl,
        const float* __restrict__ bias,
        float* __restrict__ C, unsigned short* __restrict__ Cb,
        int M, int K) {
    constexpr int BM = 64, BK = 64;
    constexpr int WN = BN / 2;
    constexpr int NF = WN / 16;
    const int wave = tid >> 6, lane = tid & 63;
    const int wrow = wave >> 1, wcol = wave & 1;
    const int l15 = lane & 15, l4 = lane >> 4;

    f32x4 acc[2][NF];
#pragma unroll
    for (int mf = 0; mf < 2; ++mf)
#pragma unroll
        for (int nf = 0; nf < NF; ++nf) acc[mf][nf] = (f32x4){0.f, 0.f, 0.f, 0.f};

    for (int k0 = 0; k0 < K; k0 += BK) {
#pragma unroll
        for (int c = 0; c < (BM * 8) / 256; ++c) {
            int ch = tid + c * 256;
            int m = ch >> 3, kc = (ch & 7) * 8;
            int gr = bm + m;
            bf16x8 hv;
            if constexpr (AF32) {
                float v[8];
                if (gr < M) {
                    const float4* src = (const float4*)(Af + (size_t)gr * K + k0 + kc);
                    float4 a0 = src[0], a1 = src[1];
                    v[0] = a0.x; v[1] = a0.y; v[2] = a0.z; v[3] = a0.w;
                    v[4] = a1.x; v[5] = a1.y; v[6] = a1.z; v[7] = a1.w;
                } else {
#pragma unroll
                    for (int j = 0; j < 8; ++j) v[j] = 0.f;
                }
#pragma unroll
                for (int j = 0; j < 8; ++j) hv[j] = (short)f2bf(v[j]);
            } else {
                if (gr < M) {
                    hv = *(const bf16x8*)(Ab + (size_t)gr * K + k0 + kc);
                } else {
                    hv = (bf16x8){0, 0, 0, 0, 0, 0, 0, 0};
                }
            }
            int byte = ((m * BK + kc) * 2) ^ ((m & 7) << 4);
            *(bf16x8*)(AhC + byte) = hv;
        }
#pragma unroll
        for (int c = 0; c < (BN * 8) / 256; ++c) {
            int ch = tid + c * 256;
            int n = ch >> 3, kc = (ch & 7) * 8;
            bf16x8 hv = *(const bf16x8*)(Bth + (size_t)n * K + k0 + kc);
            bf16x8 lv = *(const bf16x8*)(Btl + (size_t)n * K + k0 + kc);
            int byte = ((n * BK + kc) * 2) ^ ((n & 7) << 4);
            *(bf16x8*)(BhC + byte) = hv;
            *(bf16x8*)(BlC + byte) = lv;
        }
        __syncthreads();
#pragma unroll
        for (int ks = 0; ks < 2; ++ks) {
            bf16x8 ah[2], bh[NF], bl[NF];
#pragma unroll
            for (int mf = 0; mf < 2; ++mf) {
                int row = wrow * 32 + mf * 16 + l15;
                int byte = ((row * BK + ks * 32 + l4 * 8) * 2) ^ ((row & 7) << 4);
                ah[mf] = *(const bf16x8*)(AhC + byte);
            }
#pragma unroll
            for (int nf = 0; nf < NF; ++nf) {
                int n = wcol * WN + nf * 16 + l15;
                int byte = ((n * BK + ks * 32 + l4 * 8) * 2) ^ ((n & 7) << 4);
                bh[nf] = *(const bf16x8*)(BhC + byte);
                bl[nf] = *(const bf16x8*)(BlC + byte);
            }
#pragma unroll
            for (int mf = 0; mf < 2; ++mf)
#pragma unroll
                for (int nf = 0; nf < NF; ++nf) {
                    acc[mf][nf] = __builtin_amdgcn_mfma_f32_16x16x32_bf16(ah[mf], bh[nf], acc[mf][nf], 0, 0, 0);
                    acc[mf][nf] = __builtin_amdgcn_mfma_f32_16x16x32_bf16(ah[mf], bl[nf], acc[mf][nf], 0, 0, 0);
                }
        }
        __syncthreads();
    }
#pragma unroll
    for (int mf = 0; mf < 2; ++mf) {
#pragma unroll
        for (int nf = 0; nf < NF; ++nf) {
            int col = wcol * WN + nf * 16 + l15;
            float bv = 0.f;
            if constexpr (BIAS) bv = bias[col];
#pragma unroll
            for (int r = 0; r < 4; ++r) {
                int grow = bm + wrow * 32 + mf * 16 + l4 * 4 + r;
                if (grow < M) {
                    float v = acc[mf][nf][r] + bv;
                    if constexpr (RELU) v = fmaxf(v, 0.f);
                    if constexpr (WF32) C[(size_t)grow * BN + col] = v;
                    if constexpr (WB16) Cb[(size_t)grow * BN + col] = f2bf(v);
                }
            }
        }
    }
}

// plain GEMM kernel (conv layer 0)
template<int BN, bool AF32, bool RELU, bool BIAS, bool WF32, bool WB16>
__global__ __launch_bounds__(256, 4) void k_mfma_gemm(
        const float* __restrict__ Af,
        const unsigned short* __restrict__ Ab,
        const unsigned short* __restrict__ Bth,
        const unsigned short* __restrict__ Btl,
        const float* __restrict__ bias,
        float* __restrict__ C, unsigned short* __restrict__ Cb,
        int M, int K) {
    __shared__ char lds[(64 + 2 * BN) * 64 * 2];
    gemm_body<BN, AF32, RELU, BIAS, WF32, WB16>(
        lds, lds + 64 * 64 * 2, lds + (64 + BN) * 64 * 2,
        blockIdx.x * 64, threadIdx.x, Af, Ab, Bth, Btl, bias, C, Cb, M, K);
}

// MEGA_B: edge fill (family 0, 4-of-5 blocks, 1 edge/thread) + lin1 GEMM (family 1,
// 1-of-5 blocks). Best-measured arrangement (r11: 415 us total vs 422 batched-1:1
// r12, 435 fully-separate r14): fill's scatter stalls absorb lin1's MFMA+HBM phases.
constexpr int LIN1_NB = (N_NODES + 63) / 64;                 // 1563
constexpr int MEGA_B_NB = LIN1_NB * 5;                        // 7815 (fill: 6252 slots for 6250)

__global__ __launch_bounds__(256, 4) void k_mega_fill_lin1(
        const int* __restrict__ row, const int* __restrict__ col,
        int* __restrict__ cursor, const float* __restrict__ dinv,
        int2* __restrict__ edges,
        const float* __restrict__ x,
        const unsigned short* __restrict__ w1th, const unsigned short* __restrict__ w1tl,
        const float* __restrict__ b1, unsigned short* __restrict__ h0b) {
    __shared__ char lds[(64 + 2 * 128) * 64 * 2];   // 40 KB (gemm family)
    int b = blockIdx.x;
    if ((b % 5) == 4) {
        // lin1: h0b = bf16(relu(x @ w1 + b1))
        gemm_body<128, true, true, true, false, true>(
            lds, lds + 64 * 64 * 2, lds + (64 + 128) * 64 * 2,
            (b / 5) * 64, threadIdx.x, x, nullptr, w1th, w1tl, b1,
            nullptr, h0b, N_NODES, D_IN);
    } else {
        int fidx = (b / 5) * 4 + (b % 5);
        int i = fidx * 256 + (int)threadIdx.x;
        if (i < N_EDGES) {
            int r = row[i], c = col[i];
            int p = atomicAdd(&cursor[c], 1);
            int2 v;
            v.x = r;
            v.y = __float_as_int(dinv[r] * dinv[c]);
            edges[p] = v;
        }
    }
}

// ---------------- fused conv-layer-1 + logits kernel ----------------

__global__ __launch_bounds__(256, 3) void k_conv1_logits(
        const unsigned short* __restrict__ Ab,     // zb [M][128]
        const unsigned short* __restrict__ Bth,    // cw1 hi [128][128]
        const unsigned short* __restrict__ Btl,    // cw1 lo
        const unsigned short* __restrict__ W2h,    // w2 hi [64][128]
        const unsigned short* __restrict__ W2l,    // w2 lo
        const float* __restrict__ b2,
        float* __restrict__ h2, float* __restrict__ logits, int M) {
    constexpr int BM = 64, BK = 64, BN = 128, K = 128;
    constexpr int WN = BN / 2, NF = WN / 16;
    __shared__ char lds[49152];
    char* AhC = lds;                 // phase1 A: [64][64] bf16, 8 KB
    char* BhC = lds + 8192;          // phase1 B hi: [128][64], 16 KB
    char* BlC = lds + 24576;         // phase1 B lo: [128][64], 16 KB
    char* A2C = lds;                 // phase2 A: [64][128] bf16, 16 KB
    char* WhC = lds + 16384;         // phase2 w2 hi: [64][128], 16 KB
    char* WlC = lds + 32768;         // phase2 w2 lo: [64][128], 16 KB
    const int tid = threadIdx.x;
    const int wave = tid >> 6, lane = tid & 63;
    const int wrow = wave >> 1, wcol = wave & 1;
    const int l15 = lane & 15, l4 = lane >> 4;
    const int bm = blockIdx.x * BM;

    f32x4 acc[2][NF];
#pragma unroll
    for (int mf = 0; mf < 2; ++mf)
#pragma unroll
        for (int nf = 0; nf < NF; ++nf) acc[mf][nf] = (f32x4){0.f, 0.f, 0.f, 0.f};

    for (int k0 = 0; k0 < K; k0 += BK) {
#pragma unroll
        for (int c = 0; c < (BM * 8) / 256; ++c) {
            int ch = tid + c * 256;
            int m = ch >> 3, kc = (ch & 7) * 8;
            int gr = bm + m;
            bf16x8 hv;
            if (gr < M) hv = *(const bf16x8*)(Ab + (size_t)gr * K + k0 + kc);
            else        hv = (bf16x8){0, 0, 0, 0, 0, 0, 0, 0};
            int byte = ((m * BK + kc) * 2) ^ ((m & 7) << 4);
            *(bf16x8*)(AhC + byte) = hv;
        }
#pragma unroll
        for (int c = 0; c < (BN * 8) / 256; ++c) {
            int ch = tid + c * 256;
            int n = ch >> 3, kc = (ch & 7) * 8;
            bf16x8 hv = *(const bf16x8*)(Bth + (size_t)n * K + k0 + kc);
            bf16x8 lv = *(const bf16x8*)(Btl + (size_t)n * K + k0 + kc);
            int byte = ((n * BK + kc) * 2) ^ ((n & 7) << 4);
            *(bf16x8*)(BhC + byte) = hv;
            *(bf16x8*)(BlC + byte) = lv;
        }
        __syncthreads();
#pragma unroll
        for (int ks = 0; ks < 2; ++ks) {
            bf16x8 ah[2], bh[NF], bl[NF];
#pragma unroll
            for (int mf = 0; mf < 2; ++mf) {
                int row = wrow * 32 + mf * 16 + l15;
                int byte = ((row * BK + ks * 32 + l4 * 8) * 2) ^ ((row & 7) << 4);
                ah[mf] = *(const bf16x8*)(AhC + byte);
            }
#pragma unroll
            for (int nf = 0; nf < NF; ++nf) {
                int n = wcol * WN + nf * 16 + l15;
                int byte = ((n * BK + ks * 32 + l4 * 8) * 2) ^ ((n & 7) << 4);
                bh[nf] = *(const bf16x8*)(BhC + byte);
                bl[nf] = *(const bf16x8*)(BlC + byte);
            }
#pragma unroll
            for (int mf = 0; mf < 2; ++mf)
#pragma unroll
                for (int nf = 0; nf < NF; ++nf) {
                    acc[mf][nf] = __builtin_amdgcn_mfma_f32_16x16x32_bf16(ah[mf], bh[nf], acc[mf][nf], 0, 0, 0);
                    acc[mf][nf] = __builtin_amdgcn_mfma_f32_16x16x32_bf16(ah[mf], bl[nf], acc[mf][nf], 0, 0, 0);
                }
        }
        __syncthreads();
    }
    // epilogue: write h2 f32 (global) + bf16 h2 tile to LDS A2 [64][128] swizzled
#pragma unroll
    for (int mf = 0; mf < 2; ++mf) {
#pragma unroll
        for (int nf = 0; nf < NF; ++nf) {
            int col = wcol * WN + nf * 16 + l15;
#pragma unroll
            for (int r = 0; r < 4; ++r) {
                int mrow = wrow * 32 + mf * 16 + l4 * 4 + r;
                int grow = bm + mrow;
                float v = acc[mf][nf][r];
                if (grow < M) h2[(size_t)grow * BN + col] = v;
                int byte = ((mrow * 128 + col) * 2) ^ ((mrow & 7) << 4);
                *(unsigned short*)(A2C + byte) = f2bf(v);
            }
        }
    }
    // stage w2 hi/lo [64][128] into LDS
#pragma unroll
    for (int c = 0; c < 4; ++c) {
        int ch = tid + c * 256;
        int n = ch >> 4, kc = (ch & 15) * 8;
        bf16x8 hv = *(const bf16x8*)(W2h + (size_t)n * 128 + kc);
        bf16x8 lv = *(const bf16x8*)(W2l + (size_t)n * 128 + kc);
        int byte = ((n * 128 + kc) * 2) ^ ((n & 7) << 4);
        *(bf16x8*)(WhC + byte) = hv;
        *(bf16x8*)(WlC + byte) = lv;
    }
    __syncthreads();

    // phase 2: logits = A2 @ w2 + b2
    f32x4 acc2[2][2];
#pragma unroll
    for (int mf = 0; mf < 2; ++mf)
#pragma unroll
        for (int nf = 0; nf < 2; ++nf) acc2[mf][nf] = (f32x4){0.f, 0.f, 0.f, 0.f};
#pragma unroll
    for (int ks = 0; ks < 4; ++ks) {
        bf16x8 a2[2], wh[2], wl[2];
#pragma unroll
        for (int mf = 0; mf < 2; ++mf) {
            int row = wrow * 32 + mf * 16 + l15;
            int byte = ((row * 128 + ks * 32 + l4 * 8) * 2) ^ ((row & 7) << 4);
            a2[mf] = *(const bf16x8*)(A2C + byte);
        }
#pragma unroll
        for (int nf = 0; nf < 2; ++nf) {
            int n = wcol * 32 + nf * 16 + l15;
            int byte = ((n * 128 + ks * 32 + l4 * 8) * 2) ^ ((n & 7) << 4);
            wh[nf] = *(const bf16x8*)(WhC + byte);
            wl[nf] = *(const bf16x8*)(WlC + byte);
        }
#pragma unroll
        for (int mf = 0; mf < 2; ++mf)
#pragma unroll
            for (int nf = 0; nf < 2; ++nf) {
                acc2[mf][nf] = __builtin_amdgcn_mfma_f32_16x16x32_bf16(a2[mf], wh[nf], acc2[mf][nf], 0, 0, 0);
                acc2[mf][nf] = __builtin_amdgcn_mfma_f32_16x16x32_bf16(a2[mf], wl[nf], acc2[mf][nf], 0, 0, 0);
            }
    }
#pragma unroll
    for (int mf = 0; mf < 2; ++mf) {
#pragma unroll
        for (int nf = 0; nf < 2; ++nf) {
            int col = wcol * 32 + nf * 16 + l15;
            float bv = b2[col];
#pragma unroll
            for (int r = 0; r < 4; ++r) {
                int grow = bm + wrow * 32 + mf * 16 + l4 * 4 + r;
                if (grow < M)
                    logits[(size_t)grow * D_OUT + col] = acc2[mf][nf][r] + bv;
            }
        }
    }
}

// ---------------- launch ----------------

extern "C" void kernel_launch(void* const* d_in, const int* in_sizes, int n_in,
                              void* d_out, int out_size, void* d_ws, size_t ws_size,
                              hipStream_t stream) {
    const float* x  = (const float*)d_in[0];
    const int*   ei = (const int*)d_in[1];
    const float* w1 = (const float*)d_in[2];
    const float* b1 = (const float*)d_in[3];
    const float* cw = (const float*)d_in[4];
    const float* w2 = (const float*)d_in[5];
    const float* b2 = (const float*)d_in[6];
    float* out = (float*)d_out;
    const int* rowp = ei;            // source nodes
    const int* colp = ei + N_EDGES;  // target nodes

    char* p = (char*)d_ws;
    auto alloc = [&](size_t bytes) -> void* {
        void* r = (void*)p;
        p += ((bytes + 255) / 256) * 256;
        return r;
    };
    int*   deg     = (int*)  alloc((size_t)N_NODES * 4);
    int*   cursor  = (int*)  alloc((size_t)N_NODES * 4);
    int*   offsets = (int*)  alloc((size_t)(N_NODES + 1) * 4);
    int*   partials= (int*)  alloc((size_t)SCAN_NB * 4);
    int2*  edges   = (int2*) alloc((size_t)N_EDGES * 8);
    float* dinv    = (float*)alloc((size_t)N_NODES * 4);
    unsigned short* zb  = (unsigned short*)alloc((size_t)N_NODES * H_DIM * 2);
    unsigned short* h0b = (unsigned short*)alloc((size_t)N_NODES * H_DIM * 2);
    unsigned short* h1b = (unsigned short*)alloc((size_t)N_NODES * H_DIM * 2);
    unsigned short* w1th = (unsigned short*)alloc((size_t)W1_E * 2);
    unsigned short* w1tl = (unsigned short*)alloc((size_t)W1_E * 2);
    unsigned short* cwth = (unsigned short*)alloc((size_t)CW_E * 2);
    unsigned short* cwtl = (unsigned short*)alloc((size_t)CW_E * 2);
    unsigned short* w2th = (unsigned short*)alloc((size_t)W2_E * 2);
    unsigned short* w2tl = (unsigned short*)alloc((size_t)W2_E * 2);

    float* h2     = out;                              // output 0: h [N,128]
    float* logits = out + (size_t)N_NODES * H_DIM;    // output 1: [N,64]

    // deg = 0 (kernel — NOT hipMemsetAsync; see note above)
    hipLaunchKernelGGL(k_init, dim3((N_NODES + 255) / 256), dim3(256), 0, stream, deg, N_NODES);
    // CSC degree count + weight prep (co-scheduled)
    hipLaunchKernelGGL(k_mega_count_wprep, dim3(CNT_NB + WP_NB), dim3(256), 0, stream,
                       colp, deg, w1, cw, w2, w1th, w1tl, cwth, cwtl, w2th, w2tl);
    hipLaunchKernelGGL(k_scan_part,  dim3(SCAN_NB), dim3(SCAN_TPB), 0, stream, deg, partials, N_NODES);
    hipLaunchKernelGGL(k_scan_mid,   dim3(1), dim3(64), 0, stream, partials, offsets);
    hipLaunchKernelGGL(k_scan_write, dim3(SCAN_NB), dim3(SCAN_TPB), 0, stream,
                       deg, partials, offsets, cursor, dinv, N_NODES);

    // fill + lin1 co-scheduled (4:1)
    hipLaunchKernelGGL(k_mega_fill_lin1, dim3(MEGA_B_NB), dim3(256), 0, stream,
                       rowp, colp, cursor, dinv, edges, x, w1th, w1tl, b1, h0b);

    int gemmGrid = (N_NODES + 63) / 64;
    int aggGrid = (int)(((size_t)N_NODES * 64 + 255) / 256);
    // layer 0
    hipLaunchKernelGGL(k_agg, dim3(aggGrid), dim3(256), 0, stream,
                       h0b, h0b, offsets, edges, dinv, zb, N_NODES);
    hipLaunchKernelGGL((k_mfma_gemm<128, false, false, false, false, true>), dim3(gemmGrid), dim3(256), 0, stream,
                       (const float*)nullptr, zb, cwth, cwtl, (const float*)nullptr,
                       (float*)nullptr, h1b, N_NODES, H_DIM);
    // layer 1
    hipLaunchKernelGGL(k_agg, dim3(aggGrid), dim3(256), 0, stream,
                       h1b, h0b, offsets, edges, dinv, zb, N_NODES);
    // conv1 + logits fused
    hipLaunchKernelGGL(k_conv1_logits, dim3(gemmGrid), dim3(256), 0, stream,
                       zb, cwth + H_DIM * H_DIM, cwtl + H_DIM * H_DIM,
                       w2th, w2tl, b2, h2, logits, N_NODES);
}